// Round 1
// baseline (171.279 us; speedup 1.0000x reference)
//
#include <hip/hip_runtime.h>
#include <math.h>

#define S_DIM 256
#define B_DIM 16
#define F_DIM 200
#define H_DIM 100
#define ROWS (S_DIM * B_DIM)  // 4096

// ---------------------------------------------------------------------------
// K1: for each row r = s*B+b, compute Tq = tanh(input@Wq), Tk = tanh(input@Wk + bias)
// 8 rows per block, 128 threads (thread = output column h, 100 active).
// ---------------------------------------------------------------------------
__global__ __launch_bounds__(128) void k1_proj_tanh(
    const float* __restrict__ input, const float* __restrict__ Wq,
    const float* __restrict__ Wk, const float* __restrict__ bias,
    float* __restrict__ Tq, float* __restrict__ Tk)
{
    __shared__ float xs[8][200];
    const int tid = threadIdx.x;
    const int r0 = blockIdx.x * 8;
    const float4* in4 = (const float4*)input;  // row = 50 float4
    for (int idx = tid; idx < 8 * 50; idx += 128) {
        int r = idx / 50, c = idx - r * 50;
        ((float4*)xs[r])[c] = in4[(r0 + r) * 50 + c];
    }
    __syncthreads();
    const int h = tid;
    if (h >= H_DIM) return;
    float accq[8], acck[8];
    const float bv = bias[h];
#pragma unroll
    for (int r = 0; r < 8; ++r) { accq[r] = 0.f; acck[r] = bv; }
    for (int f4 = 0; f4 < 50; ++f4) {
        const int f = f4 * 4;
        const float wq0 = Wq[(f + 0) * H_DIM + h];
        const float wq1 = Wq[(f + 1) * H_DIM + h];
        const float wq2 = Wq[(f + 2) * H_DIM + h];
        const float wq3 = Wq[(f + 3) * H_DIM + h];
        const float wk0 = Wk[(f + 0) * H_DIM + h];
        const float wk1 = Wk[(f + 1) * H_DIM + h];
        const float wk2 = Wk[(f + 2) * H_DIM + h];
        const float wk3 = Wk[(f + 3) * H_DIM + h];
#pragma unroll
        for (int r = 0; r < 8; ++r) {
            const float4 xv = ((const float4*)xs[r])[f4];
            accq[r] = fmaf(xv.x, wq0, accq[r]);
            accq[r] = fmaf(xv.y, wq1, accq[r]);
            accq[r] = fmaf(xv.z, wq2, accq[r]);
            accq[r] = fmaf(xv.w, wq3, accq[r]);
            acck[r] = fmaf(xv.x, wk0, acck[r]);
            acck[r] = fmaf(xv.y, wk1, acck[r]);
            acck[r] = fmaf(xv.z, wk2, acck[r]);
            acck[r] = fmaf(xv.w, wk3, acck[r]);
        }
    }
    const float CL = 0.999999881f;  // keep |T| < 1 so denom 1+Tq*Tk never hits exact 0
#pragma unroll
    for (int r = 0; r < 8; ++r) {
        float tq = tanhf(accq[r]);
        float tk = tanhf(acck[r]);
        tq = fminf(CL, fmaxf(-CL, tq));
        tk = fminf(CL, fmaxf(-CL, tk));
        Tq[(r0 + r) * H_DIM + h] = tq;
        Tk[(r0 + r) * H_DIM + h] = tk;
    }
}

// ---------------------------------------------------------------------------
// K2: p[t,b,s] = exp( sum_h v_h * (Tq+Tk)/(1+Tq*Tk) )  for s < len[b]
// tanh(x+y) identity => 1 rcp + 3 fma per (t,s,h) element.
// Tile: 16 t x 128 s per block; grid (16, 2, B). Early-out if s-tile fully masked.
// LDS: Tk tile 128x104 f32 (53 KB) + Tq 16x100 + v  => ~60 KB, 2 blocks/CU.
// ---------------------------------------------------------------------------
__global__ __launch_bounds__(256) void k2_scores(
    const float* __restrict__ Tq, const float* __restrict__ Tk,
    const float* __restrict__ vvec, const int* __restrict__ seqlen,
    float* __restrict__ p)
{
    __shared__ float4 klds[128 * 26];  // row stride 26 float4 (=104 floats)
    __shared__ float4 qlds[16 * 25];
    __shared__ float4 vlds[25];
    const int tid = threadIdx.x;
    const int b = blockIdx.z;
    const int len = seqlen[b];
    const int s0 = blockIdx.y * 128;
    if (s0 >= len) return;  // uniform per block: whole s-tile masked
    const int t0 = blockIdx.x * 16;
    const float4* Tk4 = (const float4*)Tk;  // row = 25 float4
    const float4* Tq4 = (const float4*)Tq;
    for (int idx = tid; idx < 128 * 25; idx += 256) {
        int r = idx / 25, c = idx - r * 25;
        klds[r * 26 + c] = Tk4[((s0 + r) * B_DIM + b) * 25 + c];
    }
    for (int idx = tid; idx < 16 * 25; idx += 256) {
        int r = idx / 25, c = idx - r * 25;
        qlds[r * 25 + c] = Tq4[((t0 + r) * B_DIM + b) * 25 + c];
    }
    if (tid < 25) vlds[tid] = ((const float4*)vvec)[tid];
    __syncthreads();

    const int s = tid & 127;
    const int th = tid >> 7;  // which 8 of the 16 t rows
    float acc[8];
#pragma unroll
    for (int i = 0; i < 8; ++i) acc[i] = 0.f;

    for (int h4 = 0; h4 < 25; ++h4) {
        const float4 kk = klds[s * 26 + h4];
        const float4 vv = vlds[h4];
        float4 vk;
        vk.x = vv.x * kk.x; vk.y = vv.y * kk.y;
        vk.z = vv.z * kk.z; vk.w = vv.w * kk.w;
#pragma unroll
        for (int i = 0; i < 8; ++i) {
            const float4 tq = qlds[(th * 8 + i) * 25 + h4];
            float d, n;
            d = fmaf(tq.x, kk.x, 1.f);
            n = fmaf(tq.x, vv.x, vk.x);
            acc[i] = fmaf(n, __builtin_amdgcn_rcpf(d), acc[i]);
            d = fmaf(tq.y, kk.y, 1.f);
            n = fmaf(tq.y, vv.y, vk.y);
            acc[i] = fmaf(n, __builtin_amdgcn_rcpf(d), acc[i]);
            d = fmaf(tq.z, kk.z, 1.f);
            n = fmaf(tq.z, vv.z, vk.z);
            acc[i] = fmaf(n, __builtin_amdgcn_rcpf(d), acc[i]);
            d = fmaf(tq.w, kk.w, 1.f);
            n = fmaf(tq.w, vv.w, vk.w);
            acc[i] = fmaf(n, __builtin_amdgcn_rcpf(d), acc[i]);
        }
    }
    const int ss = s0 + s;
    if (ss < len) {
        // |e| <= sum|v_h| ~ 8  => exp never overflows; skip max-subtraction.
#pragma unroll
        for (int i = 0; i < 8; ++i) {
            const int t = t0 + th * 8 + i;
            p[(t * B_DIM + b) * S_DIM + ss] = __expf(acc[i]);
        }
    }
}

// ---------------------------------------------------------------------------
// K3: attended[t,b,f] = (sum_s p*x) / (sum_s p), s < len[b].
// 16 t per block, grid (16, B). p tile staged in LDS; row sums via 2-stage LDS.
// ---------------------------------------------------------------------------
__global__ __launch_bounds__(256) void k3_attend(
    const float* __restrict__ p, const float* __restrict__ input,
    const int* __restrict__ seqlen, float* __restrict__ att)
{
    __shared__ float plds[16][256];
    __shared__ float part[16][16];
    __shared__ float rs[16];
    const int tid = threadIdx.x;
    const int b = blockIdx.y;
    const int len = seqlen[b];
    const int t0 = blockIdx.x * 16;
    for (int idx = tid; idx < 16 * 256; idx += 256) {
        int i = idx >> 8, s = idx & 255;
        plds[i][s] = (s < len) ? p[((t0 + i) * B_DIM + b) * S_DIM + s] : 0.f;
    }
    __syncthreads();
    {
        const int i = tid >> 4, sg = tid & 15;
        float ps = 0.f;
#pragma unroll
        for (int k = 0; k < 16; ++k) ps += plds[i][sg + k * 16];
        part[i][sg] = ps;
    }
    __syncthreads();
    if (tid < 16) {
        float sum = 0.f;
#pragma unroll
        for (int k = 0; k < 16; ++k) sum += part[tid][k];
        rs[tid] = 1.0f / sum;  // len>=1 and p>0 => sum>0
    }
    __syncthreads();
    const int f = tid;
    if (f < F_DIM) {
        float acc[16];
#pragma unroll
        for (int i = 0; i < 16; ++i) acc[i] = 0.f;
        int s = 0;
        for (; s + 4 <= len; s += 4) {
            const float x0 = input[((s + 0) * B_DIM + b) * F_DIM + f];
            const float x1 = input[((s + 1) * B_DIM + b) * F_DIM + f];
            const float x2 = input[((s + 2) * B_DIM + b) * F_DIM + f];
            const float x3 = input[((s + 3) * B_DIM + b) * F_DIM + f];
#pragma unroll
            for (int i = 0; i < 16; ++i) {
                const float4 pv = *(const float4*)&plds[i][s];
                acc[i] = fmaf(pv.x, x0, acc[i]);
                acc[i] = fmaf(pv.y, x1, acc[i]);
                acc[i] = fmaf(pv.z, x2, acc[i]);
                acc[i] = fmaf(pv.w, x3, acc[i]);
            }
        }
        for (; s < len; ++s) {
            const float xv = input[(s * B_DIM + b) * F_DIM + f];
#pragma unroll
            for (int i = 0; i < 16; ++i) acc[i] = fmaf(plds[i][s], xv, acc[i]);
        }
#pragma unroll
        for (int i = 0; i < 16; ++i)
            att[((t0 + i) * B_DIM + b) * F_DIM + f] = acc[i] * rs[i];
    }
}

// ---------------------------------------------------------------------------
// K4: out[b, 0:200) = max over valid t; out[b, 200:400) = mean over valid t.
// 1 block per b, 1024 threads: 4-way split of the t loop + LDS combine.
// ---------------------------------------------------------------------------
__global__ __launch_bounds__(1024) void k4_pool(
    const float* __restrict__ att, const int* __restrict__ seqlen,
    float* __restrict__ out)
{
    __shared__ float smx[4][256];
    __shared__ float ssm[4][256];
    const int b = blockIdx.x;
    const int tid = threadIdx.x;
    const int f = tid & 255;
    const int q = tid >> 8;
    const int len = seqlen[b];
    float mx = -INFINITY, sm = 0.f;
    if (f < F_DIM) {
        for (int t = q; t < len; t += 4) {
            const float val = att[(t * B_DIM + b) * F_DIM + f];
            mx = fmaxf(mx, val);
            sm += val;
        }
    }
    smx[q][f] = mx;
    ssm[q][f] = sm;
    __syncthreads();
    if (q == 0 && f < F_DIM) {
#pragma unroll
        for (int k = 1; k < 4; ++k) {
            mx = fmaxf(mx, smx[k][f]);
            sm += ssm[k][f];
        }
        out[b * (2 * F_DIM) + f] = mx;
        out[b * (2 * F_DIM) + F_DIM + f] = sm / (float)len;
    }
}

extern "C" void kernel_launch(void* const* d_in, const int* in_sizes, int n_in,
                              void* d_out, int out_size, void* d_ws, size_t ws_size,
                              hipStream_t stream)
{
    const float* input  = (const float*)d_in[0];
    const int*   seqlen = (const int*)d_in[1];
    const float* Wq     = (const float*)d_in[2];
    const float* Wk     = (const float*)d_in[3];
    const float* bias   = (const float*)d_in[4];
    const float* vvec   = (const float*)d_in[5];
    float* out = (float*)d_out;

    float* ws = (float*)d_ws;
    float* Tq  = ws;                 // 409600 floats
    float* Tk  = ws + 409600;        // 409600 floats
    float* p   = ws + 819200;        // 1048576 floats (T,B,S)
    float* att = ws;                 // 819200 floats — aliases Tq/Tk (dead after K2)

    k1_proj_tanh<<<ROWS / 8, 128, 0, stream>>>(input, Wq, Wk, bias, Tq, Tk);
    k2_scores<<<dim3(S_DIM / 16, S_DIM / 128, B_DIM), 256, 0, stream>>>(Tq, Tk, vvec, seqlen, p);
    k3_attend<<<dim3(S_DIM / 16, B_DIM), 256, 0, stream>>>(p, input, seqlen, att);
    k4_pool<<<B_DIM, 1024, 0, stream>>>(att, seqlen, out);
}

// Round 2
// 121.852 us; speedup vs baseline: 1.4056x; 1.4056x over previous
//
#include <hip/hip_runtime.h>
#include <math.h>

#define S_DIM 256
#define B_DIM 16
#define F_DIM 200
#define H_DIM 100
#define ROWS (S_DIM * B_DIM)  // 4096

// ---------------------------------------------------------------------------
// K1: Eq = exp(2*(x@Wq)), Ek = exp(2*(x@Wk + b)) per row r = s*B+b.
// 8 rows/block, 256 threads = 2 f-halves x 128 h-lanes. x rows are read via
// uniform-address s_loads (SMEM pipe); W reads are lane-varying vector loads.
// No LDS broadcast reads anywhere; LDS only for the 2-way f-partial combine.
// ---------------------------------------------------------------------------
__global__ __launch_bounds__(256) void k1_proj_exp(
    const float* __restrict__ input, const float* __restrict__ Wq,
    const float* __restrict__ Wk, const float* __restrict__ bias,
    float* __restrict__ Eq, float* __restrict__ Ek)
{
    __shared__ float pq[8][128], pk[8][128];
    const int tid = threadIdx.x;
    const int h = tid & 127;
    const int fg = tid >> 7;                      // 0 or 1: which f-half
    const int hh = (h < H_DIM) ? h : (H_DIM - 1); // keep loads in-bounds
    const int r0 = blockIdx.x * 8;
    float accq[8], acck[8];
#pragma unroll
    for (int r = 0; r < 8; ++r) { accq[r] = 0.f; acck[r] = 0.f; }
    const int fb = fg * 100;
    for (int f4 = 0; f4 < 25; ++f4) {
        const int f = fb + f4 * 4;
        const float wq0 = Wq[(f + 0) * H_DIM + hh];
        const float wq1 = Wq[(f + 1) * H_DIM + hh];
        const float wq2 = Wq[(f + 2) * H_DIM + hh];
        const float wq3 = Wq[(f + 3) * H_DIM + hh];
        const float wk0 = Wk[(f + 0) * H_DIM + hh];
        const float wk1 = Wk[(f + 1) * H_DIM + hh];
        const float wk2 = Wk[(f + 2) * H_DIM + hh];
        const float wk3 = Wk[(f + 3) * H_DIM + hh];
#pragma unroll
        for (int r = 0; r < 8; ++r) {
            // uniform address -> s_load_dwordx4 (scalar pipe, broadcast free)
            const float4 xv = *(const float4*)&input[(r0 + r) * F_DIM + f];
            accq[r] = fmaf(xv.x, wq0, accq[r]);
            accq[r] = fmaf(xv.y, wq1, accq[r]);
            accq[r] = fmaf(xv.z, wq2, accq[r]);
            accq[r] = fmaf(xv.w, wq3, accq[r]);
            acck[r] = fmaf(xv.x, wk0, acck[r]);
            acck[r] = fmaf(xv.y, wk1, acck[r]);
            acck[r] = fmaf(xv.z, wk2, acck[r]);
            acck[r] = fmaf(xv.w, wk3, acck[r]);
        }
    }
    if (fg) {
#pragma unroll
        for (int r = 0; r < 8; ++r) { pq[r][h] = accq[r]; pk[r][h] = acck[r]; }
    }
    __syncthreads();
    if (!fg && h < H_DIM) {
        const float bv = bias[h];
#pragma unroll
        for (int r = 0; r < 8; ++r) {
            const float q = accq[r] + pq[r][h];
            const float k = acck[r] + pk[r][h] + bv;
            Eq[(r0 + r) * H_DIM + h] = __expf(2.f * q);
            Ek[(r0 + r) * H_DIM + h] = __expf(2.f * k);
        }
    }
}

// ---------------------------------------------------------------------------
// K2: p[t,b,s] = exp( sumv - 2*sum_h v_h / (Eq[t,h]*Ek[s,h] + 1) )
//   (v*tanh(q+k+b) = v - 2v/(E+1), E = exp(2(q+k+b)) = Eq*Ek; denom >= 1.)
// Block: 8 t x 64 s, 4 waves each own 2 t rows. Ek tile lane-varying from LDS
// (stride 27 f4 = no conflicts beyond the b128 floor); Eq and v via uniform
// s_loads. Both t>=len and s>=len tiles are skipped (E[len^2]/S^2 ~ 0.34).
// Inner loop: 2 VALU + 1 rcp per (t,s,h) element.
// ---------------------------------------------------------------------------
__global__ __launch_bounds__(256) void k2_scores(
    const float* __restrict__ Eq, const float* __restrict__ Ek,
    const float* __restrict__ vvec, const int* __restrict__ seqlen,
    float* __restrict__ p)
{
    __shared__ float4 klds[64 * 27];
    const int tid = threadIdx.x;
    const int b = blockIdx.z;
    const int len = seqlen[b];
    const int s0 = blockIdx.y * 64;
    const int t0 = blockIdx.x * 8;
    if (s0 >= len || t0 >= len) return;  // block-uniform
    const float4* Ek4 = (const float4*)Ek;
    for (int idx = tid; idx < 64 * 25; idx += 256) {
        int r = idx / 25, c = idx - r * 25;
        klds[r * 27 + c] = Ek4[((s0 + r) * B_DIM + b) * 25 + c];
    }
    __syncthreads();
    const int s = tid & 63;
    const int th = __builtin_amdgcn_readfirstlane(tid >> 6);  // wave id, force SGPR
    const int tbase = t0 + th * 2;
    const int ni = len - tbase;  // >=1 rows valid if > 0
    if (ni <= 0) return;         // after the only barrier — safe

    float sv = 0.f;
    for (int h4 = 0; h4 < 25; ++h4) {
        const float4 vv = *(const float4*)&vvec[h4 * 4];
        sv += (vv.x + vv.y) + (vv.z + vv.w);
    }
    float acc0 = sv, acc1 = sv;
    const float* eq0 = Eq + ((tbase + 0) * B_DIM + b) * H_DIM;
    const float* eq1 = Eq + ((tbase + 1) * B_DIM + b) * H_DIM;  // row<256 always
    for (int h4 = 0; h4 < 25; ++h4) {
        const float4 kk = klds[s * 27 + h4];
        const float4 vv = *(const float4*)&vvec[h4 * 4];
        const float4 q0 = *(const float4*)(eq0 + h4 * 4);
        const float4 q1 = *(const float4*)(eq1 + h4 * 4);
        const float m2x = -2.f * vv.x, m2y = -2.f * vv.y;
        const float m2z = -2.f * vv.z, m2w = -2.f * vv.w;
        acc0 = fmaf(m2x, __builtin_amdgcn_rcpf(fmaf(q0.x, kk.x, 1.f)), acc0);
        acc0 = fmaf(m2y, __builtin_amdgcn_rcpf(fmaf(q0.y, kk.y, 1.f)), acc0);
        acc0 = fmaf(m2z, __builtin_amdgcn_rcpf(fmaf(q0.z, kk.z, 1.f)), acc0);
        acc0 = fmaf(m2w, __builtin_amdgcn_rcpf(fmaf(q0.w, kk.w, 1.f)), acc0);
        acc1 = fmaf(m2x, __builtin_amdgcn_rcpf(fmaf(q1.x, kk.x, 1.f)), acc1);
        acc1 = fmaf(m2y, __builtin_amdgcn_rcpf(fmaf(q1.y, kk.y, 1.f)), acc1);
        acc1 = fmaf(m2z, __builtin_amdgcn_rcpf(fmaf(q1.z, kk.z, 1.f)), acc1);
        acc1 = fmaf(m2w, __builtin_amdgcn_rcpf(fmaf(q1.w, kk.w, 1.f)), acc1);
    }
    const int ss = s0 + s;
    if (ss < len) {
        p[((tbase + 0) * B_DIM + b) * S_DIM + ss] = __expf(acc0);
        if (ni > 1) p[((tbase + 1) * B_DIM + b) * S_DIM + ss] = __expf(acc1);
    }
}

// ---------------------------------------------------------------------------
// K3+K4 fused: lane = t (4 groups of 64), f-tile of 8 in registers.
//   attended[t,b,f] = (sum_s p*x)/(sum_s p); pools over t<len -> out directly.
// p is read per-lane (float4 chunks; L1 absorbs the row scatter); x rows via
// uniform s_loads. Pool: shfl_xor wave reduce + tiny LDS cross-wave combine.
// t>=len groups skip the s-loop entirely.
// ---------------------------------------------------------------------------
__global__ __launch_bounds__(256) void k3_attend_pool(
    const float* __restrict__ p, const float* __restrict__ input,
    const int* __restrict__ seqlen, float* __restrict__ out)
{
    __shared__ float lm[4][8], ls[4][8];
    const int tid = threadIdx.x;
    const int b = blockIdx.y;
    const int f0 = blockIdx.x * 8;
    const int len = seqlen[b];
    const int tg = tid >> 6, lane = tid & 63;
    const int t = tg * 64 + lane;
    float mx[8], sm[8];
#pragma unroll
    for (int j = 0; j < 8; ++j) { mx[j] = -INFINITY; sm[j] = 0.f; }

    if (tg * 64 < len) {  // wave-uniform: this t-group has valid rows
        float acc[8];
#pragma unroll
        for (int j = 0; j < 8; ++j) acc[j] = 0.f;
        float psum = 0.f;
        const float* prow = p + (t * B_DIM + b) * S_DIM;
        int s = 0;
        for (; s + 4 <= len; s += 4) {
            const float4 pv = *(const float4*)(prow + s);
            const float pvals[4] = {pv.x, pv.y, pv.z, pv.w};
            psum += (pv.x + pv.y) + (pv.z + pv.w);
#pragma unroll
            for (int q = 0; q < 4; ++q) {
                const float* xrow = &input[((s + q) * B_DIM + b) * F_DIM + f0];
                const float4 xa = *(const float4*)xrow;       // s_load
                const float4 xb = *(const float4*)(xrow + 4); // s_load
                acc[0] = fmaf(pvals[q], xa.x, acc[0]);
                acc[1] = fmaf(pvals[q], xa.y, acc[1]);
                acc[2] = fmaf(pvals[q], xa.z, acc[2]);
                acc[3] = fmaf(pvals[q], xa.w, acc[3]);
                acc[4] = fmaf(pvals[q], xb.x, acc[4]);
                acc[5] = fmaf(pvals[q], xb.y, acc[5]);
                acc[6] = fmaf(pvals[q], xb.z, acc[6]);
                acc[7] = fmaf(pvals[q], xb.w, acc[7]);
            }
        }
        for (; s < len; ++s) {  // tail 0..3
            const float pvv = prow[s];
            const float* xrow = &input[(s * B_DIM + b) * F_DIM + f0];
            const float4 xa = *(const float4*)xrow;
            const float4 xb = *(const float4*)(xrow + 4);
            psum += pvv;
            acc[0] = fmaf(pvv, xa.x, acc[0]);
            acc[1] = fmaf(pvv, xa.y, acc[1]);
            acc[2] = fmaf(pvv, xa.z, acc[2]);
            acc[3] = fmaf(pvv, xa.w, acc[3]);
            acc[4] = fmaf(pvv, xb.x, acc[4]);
            acc[5] = fmaf(pvv, xb.y, acc[5]);
            acc[6] = fmaf(pvv, xb.z, acc[6]);
            acc[7] = fmaf(pvv, xb.w, acc[7]);
        }
        // invalid lanes (t>=len) read poison rows: finite garbage, masked below
        const float rs = 1.f / psum;
        const bool tv = (t < len);
#pragma unroll
        for (int j = 0; j < 8; ++j) {
            const float a = acc[j] * rs;
            mx[j] = tv ? a : -INFINITY;
            sm[j] = tv ? a : 0.f;
        }
    }
    // 64-lane butterfly reduce (max, sum) per f
#pragma unroll
    for (int j = 0; j < 8; ++j) {
        float m = mx[j], s2 = sm[j];
        for (int off = 32; off; off >>= 1) {
            m = fmaxf(m, __shfl_xor(m, off));
            s2 += __shfl_xor(s2, off);
        }
        if (lane == 0) { lm[tg][j] = m; ls[tg][j] = s2; }
    }
    __syncthreads();
    if (tid < 8) {
        float m = lm[0][tid], s2 = ls[0][tid];
#pragma unroll
        for (int g = 1; g < 4; ++g) { m = fmaxf(m, lm[g][tid]); s2 += ls[g][tid]; }
        out[b * (2 * F_DIM) + f0 + tid] = m;
        out[b * (2 * F_DIM) + F_DIM + f0 + tid] = s2 / (float)len;
    }
}

extern "C" void kernel_launch(void* const* d_in, const int* in_sizes, int n_in,
                              void* d_out, int out_size, void* d_ws, size_t ws_size,
                              hipStream_t stream)
{
    const float* input  = (const float*)d_in[0];
    const int*   seqlen = (const int*)d_in[1];
    const float* Wq     = (const float*)d_in[2];
    const float* Wk     = (const float*)d_in[3];
    const float* bias   = (const float*)d_in[4];
    const float* vvec   = (const float*)d_in[5];
    float* out = (float*)d_out;

    float* ws = (float*)d_ws;
    float* Eq = ws;                  // 409600 floats
    float* Ek = ws + 409600;         // 409600 floats
    float* p  = ws + 819200;         // 1048576 floats [t][b][s]

    k1_proj_exp<<<ROWS / 8, 256, 0, stream>>>(input, Wq, Wk, bias, Eq, Ek);
    k2_scores<<<dim3(S_DIM / 8, S_DIM / 64, B_DIM), 256, 0, stream>>>(Eq, Ek, vvec, seqlen, p);
    k3_attend_pool<<<dim3(F_DIM / 8, B_DIM), 256, 0, stream>>>(p, input, seqlen, out);
}